// Round 1
// baseline (911.412 us; speedup 1.0000x reference)
//
#include <hip/hip_runtime.h>
#include <stdint.h>
#include <math.h>

typedef unsigned short u16;
typedef __attribute__((ext_vector_type(8))) short short8;
typedef __attribute__((ext_vector_type(4))) float floatx4;

__device__ __forceinline__ u16 f32_to_bf16(float f) {
    union { float f; uint32_t u; } v; v.f = f;
    uint32_t r = v.u + 0x7FFF + ((v.u >> 16) & 1);   // RTNE
    return (u16)(r >> 16);
}
__device__ __forceinline__ float bf16_to_f32(u16 h) {
    union { uint32_t u; float f; } v; v.u = ((uint32_t)h) << 16; return v.f;
}

__device__ __forceinline__ void gl_lds16(const u16* g, u16* l) {
    __builtin_amdgcn_global_load_lds(
        (const __attribute__((address_space(1))) void*)g,
        (__attribute__((address_space(3))) void*)l, 16, 0, 0);
}

// ---------------- prep kernels ----------------

// fp32 -> bf16 hi + bf16 lo (split precision)
__global__ void split_kernel(const float4* __restrict__ x, ushort4* __restrict__ hi,
                             ushort4* __restrict__ lo, long n4) {
    long i = (long)blockIdx.x * blockDim.x + threadIdx.x;
    if (i >= n4) return;
    float4 v = x[i];
    ushort4 h, l;
    h.x = f32_to_bf16(v.x); l.x = f32_to_bf16(v.x - bf16_to_f32(h.x));
    h.y = f32_to_bf16(v.y); l.y = f32_to_bf16(v.y - bf16_to_f32(h.y));
    h.z = f32_to_bf16(v.z); l.z = f32_to_bf16(v.z - bf16_to_f32(h.z));
    h.w = f32_to_bf16(v.w); l.w = f32_to_bf16(v.w - bf16_to_f32(h.w));
    hi[i] = h; lo[i] = l;
}

// fp32 -> bf16 (hi only)
__global__ void conv_kernel(const float4* __restrict__ x, ushort4* __restrict__ hi, long n4) {
    long i = (long)blockIdx.x * blockDim.x + threadIdx.x;
    if (i >= n4) return;
    float4 v = x[i];
    ushort4 h;
    h.x = f32_to_bf16(v.x); h.y = f32_to_bf16(v.y);
    h.z = f32_to_bf16(v.z); h.w = f32_to_bf16(v.w);
    hi[i] = h;
}

// per-batch transpose fp32 [R][C] -> bf16 [C][R]
__global__ void transpose_bf16(const float* __restrict__ src, u16* __restrict__ dst,
                               int R, int C) {
    __shared__ float tile[32][33];
    long base = (long)blockIdx.z * R * C;
    int c0 = blockIdx.x * 32, r0 = blockIdx.y * 32;
    #pragma unroll
    for (int i = threadIdx.y; i < 32; i += 8)
        tile[i][threadIdx.x] = src[base + (long)(r0 + i) * C + c0 + threadIdx.x];
    __syncthreads();
    #pragma unroll
    for (int i = threadIdx.y; i < 32; i += 8)
        dst[base + (long)(c0 + i) * R + r0 + threadIdx.x] = f32_to_bf16(tile[threadIdx.x][i]);
}

// in-place row softmax (fp32) + bf16 copy. one wave per row, 4 rows/block.
template <int VPT>
__global__ void softmax_rows(float* __restrict__ data, u16* __restrict__ outb) {
    const int SL = VPT * 64;
    int row = blockIdx.x * 4 + (threadIdx.x >> 6);
    int lane = threadIdx.x & 63;
    long base = (long)row * SL + lane;
    float v[VPT];
    #pragma unroll
    for (int i = 0; i < VPT; ++i) v[i] = data[base + i * 64];
    float m = v[0];
    #pragma unroll
    for (int i = 1; i < VPT; ++i) m = fmaxf(m, v[i]);
    #pragma unroll
    for (int off = 32; off > 0; off >>= 1) m = fmaxf(m, __shfl_xor(m, off, 64));
    float s = 0.f;
    #pragma unroll
    for (int i = 0; i < VPT; ++i) { v[i] = __expf(v[i] - m); s += v[i]; }
    #pragma unroll
    for (int off = 32; off > 0; off >>= 1) s += __shfl_xor(s, off, 64);
    float inv = 1.0f / s;
    #pragma unroll
    for (int i = 0; i < VPT; ++i) {
        float r = v[i] * inv;
        data[base + i * 64] = r;
        outb[base + i * 64] = f32_to_bf16(r);
    }
}

// ---------------- GEMM (C = A * B^T), bf16 MFMA, K-segmented ----------------
// A: [M][K] bf16 row-major (lda), B^T rows: [N][K] bf16 row-major (ldb)
// Up to 3 (A,B) pointer segments, each of length Kper, accumulated together.
// mode 0: store fp32  | mode 1: store bf16 | mode 2: store fp32 tanh(acc+bias[col])
struct GemmP {
    const u16* A[3];
    const u16* B[3];
    long strideAb, strideBb, strideCb;
    int bdiv, nseg, Kper, lda, ldb, ldc, mode;
    float* Cf; u16* Cb; const float* bias;
};

__global__ __launch_bounds__(256) void gemm_bt(GemmP p) {
    __shared__ u16 As[128 * 64];
    __shared__ u16 Bs[128 * 64];
    const int tid  = threadIdx.x;
    const int lane = tid & 63;
    const int wave = tid >> 6;
    const int quad = lane >> 4;
    const int l15  = lane & 15;
    const int wm = (wave & 1) * 64;
    const int wn = (wave >> 1) * 64;
    const int m0 = blockIdx.x * 128;
    const int n0 = blockIdx.y * 128;
    const int bz = blockIdx.z;

    floatx4 acc[4][4];
    #pragma unroll
    for (int i = 0; i < 4; ++i)
        #pragma unroll
        for (int j = 0; j < 4; ++j)
            acc[i][j] = (floatx4){0.f, 0.f, 0.f, 0.f};

    const long aoff = (long)bz * p.strideAb;
    const long boff = (long)(bz / p.bdiv) * p.strideBb;

    for (int seg = 0; seg < p.nseg; ++seg) {
        const u16* Ag = p.A[seg] + aoff + (long)m0 * p.lda;
        const u16* Bg = p.B[seg] + boff + (long)n0 * p.ldb;
        for (int k0 = 0; k0 < p.Kper; k0 += 64) {
            __syncthreads();
            #pragma unroll
            for (int i = 0; i < 4; ++i) {
                const int flat = (i * 256 + tid) * 8;
                const int r = flat >> 6, c = flat & 63;
                gl_lds16(Ag + (long)r * p.lda + k0 + c, &As[flat]);
            }
            #pragma unroll
            for (int i = 0; i < 4; ++i) {
                const int flat = (i * 256 + tid) * 8;
                const int r = flat >> 6, c = flat & 63;
                gl_lds16(Bg + (long)r * p.ldb + k0 + c, &Bs[flat]);
            }
            __syncthreads();
            #pragma unroll
            for (int kk = 0; kk < 2; ++kk) {
                short8 af[4], bfr[4];
                #pragma unroll
                for (int i = 0; i < 4; ++i)
                    af[i] = *(const short8*)&As[(wm + i * 16 + l15) * 64 + kk * 32 + quad * 8];
                #pragma unroll
                for (int i = 0; i < 4; ++i)
                    bfr[i] = *(const short8*)&Bs[(wn + i * 16 + l15) * 64 + kk * 32 + quad * 8];
                #pragma unroll
                for (int mi = 0; mi < 4; ++mi)
                    #pragma unroll
                    for (int ni = 0; ni < 4; ++ni)
                        acc[mi][ni] = __builtin_amdgcn_mfma_f32_16x16x32_bf16(
                            af[mi], bfr[ni], acc[mi][ni], 0, 0, 0);
            }
        }
    }

    const long coff = (long)bz * p.strideCb;
    const int rb = m0 + wm + quad * 4;   // + mi*16 + j
    const int cbase = n0 + wn + l15;     // + ni*16
    if (p.mode == 2) {
        #pragma unroll
        for (int ni = 0; ni < 4; ++ni) {
            const float bv = p.bias[cbase + ni * 16];
            #pragma unroll
            for (int mi = 0; mi < 4; ++mi)
                #pragma unroll
                for (int j = 0; j < 4; ++j)
                    p.Cf[coff + (long)(rb + mi * 16 + j) * p.ldc + cbase + ni * 16] =
                        tanhf(acc[mi][ni][j] + bv);
        }
    } else if (p.mode == 0) {
        #pragma unroll
        for (int ni = 0; ni < 4; ++ni)
            #pragma unroll
            for (int mi = 0; mi < 4; ++mi)
                #pragma unroll
                for (int j = 0; j < 4; ++j)
                    p.Cf[coff + (long)(rb + mi * 16 + j) * p.ldc + cbase + ni * 16] =
                        acc[mi][ni][j];
    } else {
        #pragma unroll
        for (int ni = 0; ni < 4; ++ni)
            #pragma unroll
            for (int mi = 0; mi < 4; ++mi)
                #pragma unroll
                for (int j = 0; j < 4; ++j)
                    p.Cb[coff + (long)(rb + mi * 16 + j) * p.ldc + cbase + ni * 16] =
                        f32_to_bf16(acc[mi][ni][j]);
    }
}

// ---------------- host ----------------
extern "C" void kernel_launch(void* const* d_in, const int* in_sizes, int n_in,
                              void* d_out, int out_size, void* d_ws, size_t ws_size,
                              hipStream_t stream) {
    const int BT = 80, L = 256, S = 512, H = 1024;
    const long NO   = (long)BT * L * H;   // 20971520
    const long NC1  = (long)8 * S * H;    // 4194304
    const long NW   = (long)H * 3 * H;    // 3145728
    const long NEXA = (long)BT * L * L;   // 5242880

    const float* X    = (const float*)d_in[0];
    const float* C0   = (const float*)d_in[1];
    const float* C1   = (const float*)d_in[2];
    const float* Wf   = (const float*)d_in[4];
    const float* bias = (const float*)d_in[5];

    float* out  = (float*)d_out;
    float* exa  = out + NO;           // ex_attn slot  (fp32 logits -> softmax in place)
    float* seta = exa + NEXA;         // set_attn slot

    char* wsb = (char*)d_ws;
    size_t off = 0;
    auto alloc = [&](long nbytes) -> void* {
        void* p = (void*)(wsb + off);
        off += ((size_t)nbytes + 255) & ~(size_t)255;
        return p;
    };
    u16* Xhi  = (u16*)alloc(NO * 2);
    u16* Xlo  = (u16*)alloc(NO * 2);
    u16* C0hi = (u16*)alloc(NO * 2);
    u16* C0lo = (u16*)alloc(NO * 2);
    u16* C1hi = (u16*)alloc(NC1 * 2);
    u16* C1lo = (u16*)alloc(NC1 * 2);
    u16* Wb   = (u16*)alloc(NW * 2);
    u16* exab = (u16*)alloc(NEXA * 2);
    u16* setab= (u16*)alloc((long)BT * L * S * 2);
    // aliases (lifetimes disjoint by launch order):
    u16* C0T = C0lo;   // written after GEMM1, read by GEMM3
    u16* C1T = C1lo;   // written after GEMM2, read by GEMM4
    u16* exc = Xlo;    // written by GEMM3 (Xlo last read in GEMM2)
    u16* setc = C0hi;  // written by GEMM4 (C0hi last read in GEMM1)

    // --- prep: splits + W convert ---
    split_kernel<<<(int)(NO / 4 / 256), 256, 0, stream>>>((const float4*)X, (ushort4*)Xhi, (ushort4*)Xlo, NO / 4);
    split_kernel<<<(int)(NO / 4 / 256), 256, 0, stream>>>((const float4*)C0, (ushort4*)C0hi, (ushort4*)C0lo, NO / 4);
    split_kernel<<<(int)(NC1 / 4 / 256), 256, 0, stream>>>((const float4*)C1, (ushort4*)C1hi, (ushort4*)C1lo, NC1 / 4);
    conv_kernel<<<(int)(NW / 4 / 256), 256, 0, stream>>>((const float4*)Wf, (ushort4*)Wb, NW / 4);

    // --- GEMM1: ex logits = X @ C0^T, 3-pass split, fp32 -> exa ---
    {
        GemmP p{};
        p.A[0] = Xhi;  p.A[1] = Xlo;  p.A[2] = Xhi;
        p.B[0] = C0hi; p.B[1] = C0hi; p.B[2] = C0lo;
        p.strideAb = (long)L * H; p.strideBb = (long)L * H; p.strideCb = (long)L * L;
        p.bdiv = 1; p.nseg = 3; p.Kper = H; p.lda = H; p.ldb = H; p.ldc = L; p.mode = 0;
        p.Cf = exa; p.Cb = nullptr; p.bias = nullptr;
        gemm_bt<<<dim3(L / 128, L / 128, BT), 256, 0, stream>>>(p);
    }
    softmax_rows<4><<<BT * L / 4, 256, 0, stream>>>(exa, exab);

    // --- GEMM2: set logits = X @ set_ctx^T, 3-pass split, fp32 -> seta ---
    {
        GemmP p{};
        p.A[0] = Xhi;  p.A[1] = Xlo;  p.A[2] = Xhi;
        p.B[0] = C1hi; p.B[1] = C1hi; p.B[2] = C1lo;
        p.strideAb = (long)L * H; p.strideBb = (long)S * H; p.strideCb = (long)L * S;
        p.bdiv = 10; p.nseg = 3; p.Kper = H; p.lda = H; p.ldb = H; p.ldc = S; p.mode = 0;
        p.Cf = seta; p.Cb = nullptr; p.bias = nullptr;
        gemm_bt<<<dim3(L / 128, S / 128, BT), 256, 0, stream>>>(p);
    }
    softmax_rows<8><<<BT * L / 4, 256, 0, stream>>>(seta, setab);

    // --- transposes for PV B-operands (after their source hi/lo are done) ---
    transpose_bf16<<<dim3(H / 32, L / 32, BT), dim3(32, 8), 0, stream>>>(C0, C0T, L, H);
    transpose_bf16<<<dim3(H / 32, S / 32, 8), dim3(32, 8), 0, stream>>>(C1, C1T, S, H);

    // --- GEMM3: ex_c = ex_attn @ C0  (B^T = C0T [H][L]) -> bf16 exc ---
    {
        GemmP p{};
        p.A[0] = exab; p.A[1] = exab; p.A[2] = exab;
        p.B[0] = C0T;  p.B[1] = C0T;  p.B[2] = C0T;
        p.strideAb = (long)L * L; p.strideBb = (long)H * L; p.strideCb = (long)L * H;
        p.bdiv = 1; p.nseg = 1; p.Kper = L; p.lda = L; p.ldb = L; p.ldc = H; p.mode = 1;
        p.Cf = nullptr; p.Cb = exc; p.bias = nullptr;
        gemm_bt<<<dim3(L / 128, H / 128, BT), 256, 0, stream>>>(p);
    }
    // --- GEMM4: set_c = set_attn @ set_ctx (B^T = C1T [H][S]) -> bf16 setc ---
    {
        GemmP p{};
        p.A[0] = setab; p.A[1] = setab; p.A[2] = setab;
        p.B[0] = C1T;   p.B[1] = C1T;   p.B[2] = C1T;
        p.strideAb = (long)L * S; p.strideBb = (long)H * S; p.strideCb = (long)L * H;
        p.bdiv = 10; p.nseg = 1; p.Kper = S; p.lda = S; p.ldb = S; p.ldc = H; p.mode = 1;
        p.Cf = nullptr; p.Cb = setc; p.bias = nullptr;
        gemm_bt<<<dim3(L / 128, H / 128, BT), 256, 0, stream>>>(p);
    }
    // --- GEMM5: out = tanh(concat(X, ex_c, set_c) @ W^T + b), M = 20480 ---
    {
        GemmP p{};
        p.A[0] = Xhi; p.A[1] = exc; p.A[2] = setc;
        p.B[0] = Wb;  p.B[1] = Wb + 1024; p.B[2] = Wb + 2048;
        p.strideAb = 0; p.strideBb = 0; p.strideCb = 0;
        p.bdiv = 1; p.nseg = 3; p.Kper = H; p.lda = H; p.ldb = 3 * H; p.ldc = H; p.mode = 2;
        p.Cf = out; p.Cb = nullptr; p.bias = bias;
        gemm_bt<<<dim3(BT * L / 128, H / 128, 1), 256, 0, stream>>>(p);
    }
}

// Round 2
// 847.310 us; speedup vs baseline: 1.0757x; 1.0757x over previous
//
#include <hip/hip_runtime.h>
#include <stdint.h>
#include <math.h>

typedef unsigned short u16;
typedef __attribute__((ext_vector_type(8))) short short8;
typedef __attribute__((ext_vector_type(4))) float floatx4;

__device__ __forceinline__ u16 f32_to_bf16(float f) {
    union { float f; uint32_t u; } v; v.f = f;
    uint32_t r = v.u + 0x7FFF + ((v.u >> 16) & 1);   // RTNE
    return (u16)(r >> 16);
}
__device__ __forceinline__ float bf16_to_f32(u16 h) {
    union { uint32_t u; float f; } v; v.u = ((uint32_t)h) << 16; return v.f;
}

__device__ __forceinline__ void gl_lds16(const u16* g, u16* l) {
    __builtin_amdgcn_global_load_lds(
        (const __attribute__((address_space(1))) void*)g,
        (__attribute__((address_space(3))) void*)l, 16, 0, 0);
}

// ---------------- prep kernels ----------------

__global__ void split_kernel(const float4* __restrict__ x, ushort4* __restrict__ hi,
                             ushort4* __restrict__ lo, long n4) {
    long i = (long)blockIdx.x * blockDim.x + threadIdx.x;
    if (i >= n4) return;
    float4 v = x[i];
    ushort4 h, l;
    h.x = f32_to_bf16(v.x); l.x = f32_to_bf16(v.x - bf16_to_f32(h.x));
    h.y = f32_to_bf16(v.y); l.y = f32_to_bf16(v.y - bf16_to_f32(h.y));
    h.z = f32_to_bf16(v.z); l.z = f32_to_bf16(v.z - bf16_to_f32(h.z));
    h.w = f32_to_bf16(v.w); l.w = f32_to_bf16(v.w - bf16_to_f32(h.w));
    hi[i] = h; lo[i] = l;
}

__global__ void conv_kernel(const float4* __restrict__ x, ushort4* __restrict__ hi, long n4) {
    long i = (long)blockIdx.x * blockDim.x + threadIdx.x;
    if (i >= n4) return;
    float4 v = x[i];
    ushort4 h;
    h.x = f32_to_bf16(v.x); h.y = f32_to_bf16(v.y);
    h.z = f32_to_bf16(v.z); h.w = f32_to_bf16(v.w);
    hi[i] = h;
}

__global__ void transpose_bf16(const float* __restrict__ src, u16* __restrict__ dst,
                               int R, int C) {
    __shared__ float tile[32][33];
    long base = (long)blockIdx.z * R * C;
    int c0 = blockIdx.x * 32, r0 = blockIdx.y * 32;
    #pragma unroll
    for (int i = threadIdx.y; i < 32; i += 8)
        tile[i][threadIdx.x] = src[base + (long)(r0 + i) * C + c0 + threadIdx.x];
    __syncthreads();
    #pragma unroll
    for (int i = threadIdx.y; i < 32; i += 8)
        dst[base + (long)(c0 + i) * R + r0 + threadIdx.x] = f32_to_bf16(tile[threadIdx.x][i]);
}

template <int VPT>
__global__ void softmax_rows(float* __restrict__ data, u16* __restrict__ outb) {
    const int SL = VPT * 64;
    int row = blockIdx.x * 4 + (threadIdx.x >> 6);
    int lane = threadIdx.x & 63;
    long base = (long)row * SL + lane;
    float v[VPT];
    #pragma unroll
    for (int i = 0; i < VPT; ++i) v[i] = data[base + i * 64];
    float m = v[0];
    #pragma unroll
    for (int i = 1; i < VPT; ++i) m = fmaxf(m, v[i]);
    #pragma unroll
    for (int off = 32; off > 0; off >>= 1) m = fmaxf(m, __shfl_xor(m, off, 64));
    float s = 0.f;
    #pragma unroll
    for (int i = 0; i < VPT; ++i) { v[i] = __expf(v[i] - m); s += v[i]; }
    #pragma unroll
    for (int off = 32; off > 0; off >>= 1) s += __shfl_xor(s, off, 64);
    float inv = 1.0f / s;
    #pragma unroll
    for (int i = 0; i < VPT; ++i) {
        float r = v[i] * inv;
        data[base + i * 64] = r;
        outb[base + i * 64] = f32_to_bf16(r);
    }
}

// ---------------- GEMM (C = A * B^T), bf16 MFMA, K-segmented ----------------
// A: [M][K] bf16 row-major (lda), B^T rows: [N][K] bf16 row-major (ldb)
// LDS layout XOR-swizzled: LDS(r, chunk) = G(r, chunk ^ (r&7)); chunk = 8 u16 (16B).
// Swizzle applied on the GLOBAL source address in staging (lane-linear LDS dest is
// required by global_load_lds) and on the ds_read address in the fragment loads.
// Bank math: byte row stride 128 = 32 banks, so pre-swizzle bank = quad*4 only
// (16 lanes / 4-bank group, 2x LDS time, 4.7e7 conflicts measured R1). Post-swizzle
// each 4-bank group serves exactly 8/64 lanes -> uniform, free.
// n-tile = blockIdx.x so consecutive blocks share the A m-tile (L2 reuse).
// mode 0: store fp32 | mode 1: store bf16 | mode 2: store fp32 tanh(acc+bias[col])
struct GemmP {
    const u16* A[3];
    const u16* B[3];
    long strideAb, strideBb, strideCb;
    int bdiv, nseg, Kper, lda, ldb, ldc, mode;
    float* Cf; u16* Cb; const float* bias;
};

__global__ __launch_bounds__(256) void gemm_bt(GemmP p) {
    __shared__ u16 As[128 * 64];
    __shared__ u16 Bs[128 * 64];
    const int tid  = threadIdx.x;
    const int lane = tid & 63;
    const int wave = tid >> 6;
    const int quad = lane >> 4;
    const int l15  = lane & 15;
    const int wm = (wave & 1) * 64;
    const int wn = (wave >> 1) * 64;
    const int n0 = blockIdx.x * 128;
    const int m0 = blockIdx.y * 128;
    const int bz = blockIdx.z;

    // staging: thread writes LDS chunk (r = i*32 + tid/8, chunk = tid&7);
    // reads global chunk (tid&7) ^ (r&7) = (tid&7) ^ ((tid>>3)&7).
    const int stg_r8 = tid >> 3;                       // r within 32-row slab
    const int stg_c  = ((tid & 7) ^ (stg_r8 & 7)) * 8; // swizzled source column
    const int xorl   = l15 & 7;                        // read-side xor (const/lane)

    floatx4 acc[4][4];
    #pragma unroll
    for (int i = 0; i < 4; ++i)
        #pragma unroll
        for (int j = 0; j < 4; ++j)
            acc[i][j] = (floatx4){0.f, 0.f, 0.f, 0.f};

    const long aoff = (long)bz * p.strideAb;
    const long boff = (long)(bz / p.bdiv) * p.strideBb;

    for (int seg = 0; seg < p.nseg; ++seg) {
        const u16* Ag = p.A[seg] + aoff + (long)m0 * p.lda;
        const u16* Bg = p.B[seg] + boff + (long)n0 * p.ldb;
        for (int k0 = 0; k0 < p.Kper; k0 += 64) {
            __syncthreads();
            #pragma unroll
            for (int i = 0; i < 4; ++i) {
                const int r = i * 32 + stg_r8;
                gl_lds16(Ag + (long)r * p.lda + k0 + stg_c, &As[(i * 256 + tid) * 8]);
            }
            #pragma unroll
            for (int i = 0; i < 4; ++i) {
                const int r = i * 32 + stg_r8;
                gl_lds16(Bg + (long)r * p.ldb + k0 + stg_c, &Bs[(i * 256 + tid) * 8]);
            }
            __syncthreads();
            #pragma unroll
            for (int kk = 0; kk < 2; ++kk) {
                const int cs = ((kk * 4 + quad) ^ xorl) * 8;  // swizzled chunk offset
                short8 af[4], bfr[4];
                #pragma unroll
                for (int i = 0; i < 4; ++i)
                    af[i] = *(const short8*)&As[(wm + i * 16 + l15) * 64 + cs];
                #pragma unroll
                for (int i = 0; i < 4; ++i)
                    bfr[i] = *(const short8*)&Bs[(wn + i * 16 + l15) * 64 + cs];
                #pragma unroll
                for (int mi = 0; mi < 4; ++mi)
                    #pragma unroll
                    for (int ni = 0; ni < 4; ++ni)
                        acc[mi][ni] = __builtin_amdgcn_mfma_f32_16x16x32_bf16(
                            af[mi], bfr[ni], acc[mi][ni], 0, 0, 0);
            }
        }
    }

    const long coff = (long)bz * p.strideCb;
    const int rb = m0 + wm + quad * 4;   // + mi*16 + j
    const int cbase = n0 + wn + l15;     // + ni*16
    if (p.mode == 2) {
        #pragma unroll
        for (int ni = 0; ni < 4; ++ni) {
            const float bv = p.bias[cbase + ni * 16];
            #pragma unroll
            for (int mi = 0; mi < 4; ++mi)
                #pragma unroll
                for (int j = 0; j < 4; ++j)
                    p.Cf[coff + (long)(rb + mi * 16 + j) * p.ldc + cbase + ni * 16] =
                        tanhf(acc[mi][ni][j] + bv);
        }
    } else if (p.mode == 0) {
        #pragma unroll
        for (int ni = 0; ni < 4; ++ni)
            #pragma unroll
            for (int mi = 0; mi < 4; ++mi)
                #pragma unroll
                for (int j = 0; j < 4; ++j)
                    p.Cf[coff + (long)(rb + mi * 16 + j) * p.ldc + cbase + ni * 16] =
                        acc[mi][ni][j];
    } else {
        #pragma unroll
        for (int ni = 0; ni < 4; ++ni)
            #pragma unroll
            for (int mi = 0; mi < 4; ++mi)
                #pragma unroll
                for (int j = 0; j < 4; ++j)
                    p.Cb[coff + (long)(rb + mi * 16 + j) * p.ldc + cbase + ni * 16] =
                        f32_to_bf16(acc[mi][ni][j]);
    }
}

// ---------------- host ----------------
extern "C" void kernel_launch(void* const* d_in, const int* in_sizes, int n_in,
                              void* d_out, int out_size, void* d_ws, size_t ws_size,
                              hipStream_t stream) {
    const int BT = 80, L = 256, S = 512, H = 1024;
    const long NO   = (long)BT * L * H;   // 20971520
    const long NC1  = (long)8 * S * H;    // 4194304
    const long NW   = (long)H * 3 * H;    // 3145728
    const long NEXA = (long)BT * L * L;   // 5242880

    const float* X    = (const float*)d_in[0];
    const float* C0   = (const float*)d_in[1];
    const float* C1   = (const float*)d_in[2];
    const float* Wf   = (const float*)d_in[4];
    const float* bias = (const float*)d_in[5];

    float* out  = (float*)d_out;
    float* exa  = out + NO;           // ex_attn slot  (fp32 logits -> softmax in place)
    float* seta = exa + NEXA;         // set_attn slot

    char* wsb = (char*)d_ws;
    size_t off = 0;
    auto alloc = [&](long nbytes) -> void* {
        void* p = (void*)(wsb + off);
        off += ((size_t)nbytes + 255) & ~(size_t)255;
        return p;
    };
    u16* Xhi  = (u16*)alloc(NO * 2);
    u16* Xlo  = (u16*)alloc(NO * 2);
    u16* C0hi = (u16*)alloc(NO * 2);
    u16* C0lo = (u16*)alloc(NO * 2);
    u16* C1hi = (u16*)alloc(NC1 * 2);
    u16* C1lo = (u16*)alloc(NC1 * 2);
    u16* Wb   = (u16*)alloc(NW * 2);
    u16* exab = (u16*)alloc(NEXA * 2);
    u16* setab= (u16*)alloc((long)BT * L * S * 2);
    // aliases (lifetimes disjoint by launch order):
    u16* C0T = C0lo;   // written after GEMM1, read by GEMM3
    u16* C1T = C1lo;   // written after GEMM2, read by GEMM4
    u16* exc = Xlo;    // written by GEMM3 (Xlo last read in GEMM2)
    u16* setc = C0hi;  // written by GEMM4 (C0hi last read in GEMM1)

    // --- prep: splits + W convert ---
    split_kernel<<<(int)(NO / 4 / 256), 256, 0, stream>>>((const float4*)X, (ushort4*)Xhi, (ushort4*)Xlo, NO / 4);
    split_kernel<<<(int)(NO / 4 / 256), 256, 0, stream>>>((const float4*)C0, (ushort4*)C0hi, (ushort4*)C0lo, NO / 4);
    split_kernel<<<(int)(NC1 / 4 / 256), 256, 0, stream>>>((const float4*)C1, (ushort4*)C1hi, (ushort4*)C1lo, NC1 / 4);
    conv_kernel<<<(int)(NW / 4 / 256), 256, 0, stream>>>((const float4*)Wf, (ushort4*)Wb, NW / 4);

    // --- GEMM1: ex logits = X @ C0^T, 3-pass split, fp32 -> exa ---
    {
        GemmP p{};
        p.A[0] = Xhi;  p.A[1] = Xlo;  p.A[2] = Xhi;
        p.B[0] = C0hi; p.B[1] = C0hi; p.B[2] = C0lo;
        p.strideAb = (long)L * H; p.strideBb = (long)L * H; p.strideCb = (long)L * L;
        p.bdiv = 1; p.nseg = 3; p.Kper = H; p.lda = H; p.ldb = H; p.ldc = L; p.mode = 0;
        p.Cf = exa; p.Cb = nullptr; p.bias = nullptr;
        gemm_bt<<<dim3(L / 128, L / 128, BT), 256, 0, stream>>>(p);
    }
    softmax_rows<4><<<BT * L / 4, 256, 0, stream>>>(exa, exab);

    // --- GEMM2: set logits = X @ set_ctx^T, 3-pass split, fp32 -> seta ---
    {
        GemmP p{};
        p.A[0] = Xhi;  p.A[1] = Xlo;  p.A[2] = Xhi;
        p.B[0] = C1hi; p.B[1] = C1hi; p.B[2] = C1lo;
        p.strideAb = (long)L * H; p.strideBb = (long)S * H; p.strideCb = (long)L * S;
        p.bdiv = 10; p.nseg = 3; p.Kper = H; p.lda = H; p.ldb = H; p.ldc = S; p.mode = 0;
        p.Cf = seta; p.Cb = nullptr; p.bias = nullptr;
        gemm_bt<<<dim3(S / 128, L / 128, BT), 256, 0, stream>>>(p);
    }
    softmax_rows<8><<<BT * L / 4, 256, 0, stream>>>(seta, setab);

    // --- transposes for PV B-operands (after their source hi/lo are done) ---
    transpose_bf16<<<dim3(H / 32, L / 32, BT), dim3(32, 8), 0, stream>>>(C0, C0T, L, H);
    transpose_bf16<<<dim3(H / 32, S / 32, 8), dim3(32, 8), 0, stream>>>(C1, C1T, S, H);

    // --- GEMM3: ex_c = ex_attn @ C0  (B^T = C0T [H][L]) -> bf16 exc ---
    {
        GemmP p{};
        p.A[0] = exab; p.A[1] = exab; p.A[2] = exab;
        p.B[0] = C0T;  p.B[1] = C0T;  p.B[2] = C0T;
        p.strideAb = (long)L * L; p.strideBb = (long)H * L; p.strideCb = (long)L * H;
        p.bdiv = 1; p.nseg = 1; p.Kper = L; p.lda = L; p.ldb = L; p.ldc = H; p.mode = 1;
        p.Cf = nullptr; p.Cb = exc; p.bias = nullptr;
        gemm_bt<<<dim3(H / 128, L / 128, BT), 256, 0, stream>>>(p);
    }
    // --- GEMM4: set_c = set_attn @ set_ctx (B^T = C1T [H][S]) -> bf16 setc ---
    {
        GemmP p{};
        p.A[0] = setab; p.A[1] = setab; p.A[2] = setab;
        p.B[0] = C1T;   p.B[1] = C1T;   p.B[2] = C1T;
        p.strideAb = (long)L * S; p.strideBb = (long)H * S; p.strideCb = (long)L * H;
        p.bdiv = 10; p.nseg = 1; p.Kper = S; p.lda = S; p.ldb = S; p.ldc = H; p.mode = 1;
        p.Cf = nullptr; p.Cb = setc; p.bias = nullptr;
        gemm_bt<<<dim3(H / 128, L / 128, BT), 256, 0, stream>>>(p);
    }
    // --- GEMM5: out = tanh(concat(X, ex_c, set_c) @ W^T + b), M = 20480 ---
    {
        GemmP p{};
        p.A[0] = Xhi; p.A[1] = exc; p.A[2] = setc;
        p.B[0] = Wb;  p.B[1] = Wb + 1024; p.B[2] = Wb + 2048;
        p.strideAb = 0; p.strideBb = 0; p.strideCb = 0;
        p.bdiv = 1; p.nseg = 3; p.Kper = H; p.lda = H; p.ldb = 3 * H; p.ldc = H; p.mode = 2;
        p.Cf = out; p.Cb = nullptr; p.bias = bias;
        gemm_bt<<<dim3(H / 128, BT * L / 128, 1), 256, 0, stream>>>(p);
    }
}